// Round 1
// baseline (1104.151 us; speedup 1.0000x reference)
//
#include <hip/hip_runtime.h>
#include <hip/hip_bf16.h>

// GCN 2-layer encoder, f32 pipeline.
// Layer: h = x@W ; agg[d] += dis[s]*dis[d]*h[s] over edges ; += dis[n]^2*h[n] (self loop) + b ; relu (layer1 only)

__global__ void fill_kernel(float* __restrict__ p, float v, long n) {
    long i = (long)blockIdx.x * blockDim.x + threadIdx.x;
    long stride = (long)gridDim.x * blockDim.x;
    for (; i < n; i += stride) p[i] = v;
}

__global__ void deg_accum(const int* __restrict__ dst, float* __restrict__ deg, int E) {
    int i = blockIdx.x * blockDim.x + threadIdx.x;
    if (i < E) atomicAdd(&deg[dst[i]], 1.0f);
}

__global__ void rsqrt_kernel(float* __restrict__ p, int n) {
    int i = blockIdx.x * blockDim.x + threadIdx.x;
    if (i < n) p[i] = rsqrtf(p[i]);   // deg >= 1 always (self loop)
}

// C[M x BN] = A[M x K] @ B[K x BN], grid.x tiles M, BN == full N of the problem.
template<int BM, int BN, int BK, int TM, int TN>
__global__ __launch_bounds__(256) void gemm_f32(
    const float* __restrict__ A, const float* __restrict__ B,
    float* __restrict__ C, int M, int K) {
    constexpr int NT = (BM / TM) * (BN / TN);
    static_assert(NT == 256, "block must be 256 threads");
    __shared__ float As[BK][BM];
    __shared__ float Bs[BK][BN];
    const int tid = threadIdx.x;
    const int bm = blockIdx.x * BM;
    constexpr int NTN = BN / TN;
    const int n0 = (tid % NTN) * TN;
    const int m0 = (tid / NTN) * TM;

    float acc[TM][TN];
#pragma unroll
    for (int i = 0; i < TM; i++)
#pragma unroll
        for (int j = 0; j < TN; j++) acc[i][j] = 0.f;

    for (int k0 = 0; k0 < K; k0 += BK) {
        // stage A tile (transposed to k-major for contiguous frag reads)
        for (int i = tid; i < BM * BK; i += NT) {
            int r = i / BK, kk = i - r * BK;
            int row = bm + r;
            As[kk][r] = (row < M) ? A[(size_t)row * K + k0 + kk] : 0.f;
        }
        // stage B tile (coalesced)
        for (int i = tid; i < BK * BN; i += NT) {
            int kk = i / BN, n = i - kk * BN;
            Bs[kk][n] = B[(size_t)(k0 + kk) * BN + n];
        }
        __syncthreads();
#pragma unroll
        for (int kk = 0; kk < BK; kk++) {
            float a[TM], b[TN];
#pragma unroll
            for (int i = 0; i < TM; i++) a[i] = As[kk][m0 + i];
#pragma unroll
            for (int j = 0; j < TN; j++) b[j] = Bs[kk][n0 + j];
#pragma unroll
            for (int i = 0; i < TM; i++)
#pragma unroll
                for (int j = 0; j < TN; j++) acc[i][j] += a[i] * b[j];
        }
        __syncthreads();
    }
#pragma unroll
    for (int i = 0; i < TM; i++) {
        int row = bm + m0 + i;
        if (row < M) {
#pragma unroll
            for (int j = 0; j < TN; j += 4) {
                float4 v = make_float4(acc[i][j], acc[i][j + 1], acc[i][j + 2], acc[i][j + 3]);
                *(float4*)&C[(size_t)row * BN + n0 + j] = v;
            }
        }
    }
}

// one wave per edge; F=128 -> float2 per lane, F=64 -> float per lane
template<int F>
__global__ void scatter_edges(const int* __restrict__ src, const int* __restrict__ dst,
                              const float* __restrict__ dis, const float* __restrict__ h,
                              float* __restrict__ out, int E) {
    int gid = blockIdx.x * blockDim.x + threadIdx.x;
    int e = gid >> 6, lane = gid & 63;
    if (e >= E) return;
    int s = src[e], d = dst[e];
    float w = dis[s] * dis[d];
    if constexpr (F == 128) {
        const float2 v = *(const float2*)&h[(size_t)s * 128 + lane * 2];
        float* o = &out[(size_t)d * 128 + lane * 2];
        atomicAdd(o, w * v.x);
        atomicAdd(o + 1, w * v.y);
    } else {
        atomicAdd(&out[(size_t)d * F + lane], w * h[(size_t)s * F + lane]);
    }
}

__global__ void finalize1(float* __restrict__ agg, const float* __restrict__ h,
                          const float* __restrict__ dis, const float* __restrict__ b,
                          int Nn) {
    int idx = blockIdx.x * blockDim.x + threadIdx.x;
    if (idx >= Nn * 128) return;
    int n = idx >> 7, f = idx & 127;
    float ds = dis[n];
    float v = agg[idx] + ds * ds * h[idx] + b[f];
    agg[idx] = fmaxf(v, 0.f);   // relu, in place
}

__global__ void finalize2(float* __restrict__ out, const float* __restrict__ h,
                          const float* __restrict__ dis, const float* __restrict__ b,
                          int Nn) {
    int idx = blockIdx.x * blockDim.x + threadIdx.x;
    if (idx >= Nn * 64) return;
    int n = idx >> 6, f = idx & 63;
    float ds = dis[n];
    out[idx] += ds * ds * h[idx] + b[f];
}

extern "C" void kernel_launch(void* const* d_in, const int* in_sizes, int n_in,
                              void* d_out, int out_size, void* d_ws, size_t ws_size,
                              hipStream_t stream) {
    const float* x  = (const float*)d_in[0];
    const int*   ei = (const int*)d_in[1];
    const float* W1 = (const float*)d_in[2];
    const float* b1 = (const float*)d_in[3];
    const float* W2 = (const float*)d_in[4];
    const float* b2 = (const float*)d_in[5];

    const int IN = 500, H = 128, OUT = 64;
    const int Nn = in_sizes[0] / IN;     // 50000
    const int E  = in_sizes[1] / 2;      // 800000
    const int* src  = ei;
    const int* dstp = ei + E;

    // workspace layout: dis | h1 | agg1 ; h2 reuses h1 region after finalize1
    float* dis  = (float*)d_ws;
    float* h1   = dis + (size_t)((Nn + 63) / 64) * 64;
    float* agg1 = h1 + (size_t)Nn * H;
    float* h2   = h1;
    float* out  = (float*)d_out;

    // ---- degree / normalization ----
    fill_kernel<<<(Nn + 255) / 256, 256, 0, stream>>>(dis, 1.0f, Nn);  // self loop
    deg_accum<<<(E + 255) / 256, 256, 0, stream>>>(dstp, dis, E);
    rsqrt_kernel<<<(Nn + 255) / 256, 256, 0, stream>>>(dis, Nn);

    // ---- layer 1 ----
    gemm_f32<64, 128, 10, 4, 8><<<(Nn + 63) / 64, 256, 0, stream>>>(x, W1, h1, Nn, IN);
    fill_kernel<<<2048, 256, 0, stream>>>(agg1, 0.f, (long)Nn * H);
    scatter_edges<128><<<(E + 3) / 4, 256, 0, stream>>>(src, dstp, dis, h1, agg1, E);
    finalize1<<<(Nn * H + 255) / 256, 256, 0, stream>>>(agg1, h1, dis, b1, Nn);

    // ---- layer 2 ----
    gemm_f32<64, 64, 16, 4, 4><<<(Nn + 63) / 64, 256, 0, stream>>>(agg1, W2, h2, Nn, H);
    fill_kernel<<<2048, 256, 0, stream>>>(out, 0.f, (long)Nn * OUT);
    scatter_edges<64><<<(E + 3) / 4, 256, 0, stream>>>(src, dstp, dis, h2, out, E);
    finalize2<<<(Nn * OUT + 255) / 256, 256, 0, stream>>>(out, h2, dis, b2, Nn);
}

// Round 2
// 465.240 us; speedup vs baseline: 2.3733x; 2.3733x over previous
//
#include <hip/hip_runtime.h>
#include <hip/hip_bf16.h>

// GCN 2-layer encoder, f32 pipeline, CSR-gather aggregation (no feature atomics).
// Layer: h = x@W ; out[n] = dis[n]*(sum_{e:dst=n} dis[src]*h[src] + dis[n]*h[n]) + b ; relu (layer1)

__global__ void fill_int(int* __restrict__ p, int v, int n) {
    int i = blockIdx.x * blockDim.x + threadIdx.x;
    if (i < n) p[i] = v;
}

__global__ void deg_accum_i(const int* __restrict__ dst, int* __restrict__ deg, int E) {
    int i = blockIdx.x * blockDim.x + threadIdx.x;
    if (i < E) atomicAdd(&deg[dst[i]], 1);
}

// in-place: int degree -> float rsqrt(deg+1)  (self loop adds 1)
__global__ void make_dis(int* __restrict__ deg, int N) {
    int i = blockIdx.x * blockDim.x + threadIdx.x;
    if (i < N) {
        int d = deg[i];
        ((float*)deg)[i] = rsqrtf((float)(d + 1));
    }
}

// single-block exclusive scan of N ints -> rp[0..N]
__global__ __launch_bounds__(1024) void scan_block(const int* __restrict__ deg, int* __restrict__ rp, int N) {
    __shared__ int wsum[16];
    __shared__ int carry_s;
    const int tid = threadIdx.x;
    const int lane = tid & 63;
    const int wid = tid >> 6;
    if (tid == 0) carry_s = 0;
    __syncthreads();
    for (int start = 0; start < N; start += 1024) {
        int i = start + tid;
        int v = (i < N) ? deg[i] : 0;
        int x = v;
#pragma unroll
        for (int off = 1; off < 64; off <<= 1) {
            int t = __shfl_up(x, off, 64);
            if (lane >= off) x += t;
        }
        if (lane == 63) wsum[wid] = x;
        __syncthreads();
        if (tid < 16) {
            int y = wsum[tid];
#pragma unroll
            for (int off = 1; off < 16; off <<= 1) {
                int t = __shfl_up(y, off, 16);
                if (tid >= off) y += t;
            }
            wsum[tid] = y;
        }
        __syncthreads();
        int base = carry_s + (wid ? wsum[wid - 1] : 0);
        if (i < N) rp[i] = base + x - v;  // exclusive
        __syncthreads();
        if (tid == 0) carry_s += wsum[15];
        __syncthreads();
    }
    if (tid == 0) rp[N] = carry_s;
}

__global__ void copy_int(const int* __restrict__ a, int* __restrict__ b, int n) {
    int i = blockIdx.x * blockDim.x + threadIdx.x;
    if (i < n) b[i] = a[i];
}

__global__ void csr_fill(const int* __restrict__ src, const int* __restrict__ dst,
                         int* __restrict__ cursor, int* __restrict__ csr_src, int E) {
    int e = blockIdx.x * blockDim.x + threadIdx.x;
    if (e < E) {
        int pos = atomicAdd(&cursor[dst[e]], 1);
        csr_src[pos] = src[e];
    }
}

// C[M x BN] = A[M x K] @ B[K x BN], grid.x tiles M, BN == full N of the problem.
template<int BM, int BN, int BK, int TM, int TN>
__global__ __launch_bounds__(256) void gemm_f32(
    const float* __restrict__ A, const float* __restrict__ B,
    float* __restrict__ C, int M, int K) {
    constexpr int NT = (BM / TM) * (BN / TN);
    static_assert(NT == 256, "block must be 256 threads");
    __shared__ float As[BK][BM];
    __shared__ float Bs[BK][BN];
    const int tid = threadIdx.x;
    const int bm = blockIdx.x * BM;
    constexpr int NTN = BN / TN;
    const int n0 = (tid % NTN) * TN;
    const int m0 = (tid / NTN) * TM;

    float acc[TM][TN];
#pragma unroll
    for (int i = 0; i < TM; i++)
#pragma unroll
        for (int j = 0; j < TN; j++) acc[i][j] = 0.f;

    for (int k0 = 0; k0 < K; k0 += BK) {
        for (int i = tid; i < BM * BK; i += NT) {
            int r = i / BK, kk = i - r * BK;
            int row = bm + r;
            As[kk][r] = (row < M) ? A[(size_t)row * K + k0 + kk] : 0.f;
        }
        for (int i = tid; i < BK * BN; i += NT) {
            int kk = i / BN, n = i - kk * BN;
            Bs[kk][n] = B[(size_t)(k0 + kk) * BN + n];
        }
        __syncthreads();
#pragma unroll
        for (int kk = 0; kk < BK; kk++) {
            float a[TM], b[TN];
#pragma unroll
            for (int i = 0; i < TM; i++) a[i] = As[kk][m0 + i];
#pragma unroll
            for (int j = 0; j < TN; j++) b[j] = Bs[kk][n0 + j];
#pragma unroll
            for (int i = 0; i < TM; i++)
#pragma unroll
                for (int j = 0; j < TN; j++) acc[i][j] += a[i] * b[j];
        }
        __syncthreads();
    }
#pragma unroll
    for (int i = 0; i < TM; i++) {
        int row = bm + m0 + i;
        if (row < M) {
#pragma unroll
            for (int j = 0; j < TN; j += 4) {
                float4 v = make_float4(acc[i][j], acc[i][j + 1], acc[i][j + 2], acc[i][j + 3]);
                *(float4*)&C[(size_t)row * BN + n0 + j] = v;
            }
        }
    }
}

// one wave per dst node, lanes across 128 features (float2/lane); fused self-loop+bias+relu
__global__ __launch_bounds__(256) void gather128(
    const int* __restrict__ rp, const int* __restrict__ csr,
    const float* __restrict__ dis, const float* __restrict__ h,
    const float* __restrict__ bias, float* __restrict__ out, int Nn) {
    int n = (blockIdx.x * 256 + threadIdx.x) >> 6;
    int lane = threadIdx.x & 63;
    if (n >= Nn) return;
    int beg = rp[n], end = rp[n + 1];
    float accx = 0.f, accy = 0.f;
    int j = beg;
    for (; j + 1 < end; j += 2) {
        int s0 = csr[j], s1 = csr[j + 1];
        float w0 = dis[s0], w1 = dis[s1];
        float2 v0 = *(const float2*)&h[(size_t)s0 * 128 + lane * 2];
        float2 v1 = *(const float2*)&h[(size_t)s1 * 128 + lane * 2];
        accx = fmaf(w0, v0.x, accx); accy = fmaf(w0, v0.y, accy);
        accx = fmaf(w1, v1.x, accx); accy = fmaf(w1, v1.y, accy);
    }
    if (j < end) {
        int s = csr[j];
        float w = dis[s];
        float2 v = *(const float2*)&h[(size_t)s * 128 + lane * 2];
        accx = fmaf(w, v.x, accx); accy = fmaf(w, v.y, accy);
    }
    float dn = dis[n];
    float2 hv = *(const float2*)&h[(size_t)n * 128 + lane * 2];
    float2 o;
    o.x = fmaxf(dn * (accx + dn * hv.x) + bias[lane * 2], 0.f);
    o.y = fmaxf(dn * (accy + dn * hv.y) + bias[lane * 2 + 1], 0.f);
    *(float2*)&out[(size_t)n * 128 + lane * 2] = o;
}

// one wave per dst node, lanes across 64 features; fused self-loop+bias (no relu)
__global__ __launch_bounds__(256) void gather64(
    const int* __restrict__ rp, const int* __restrict__ csr,
    const float* __restrict__ dis, const float* __restrict__ h,
    const float* __restrict__ bias, float* __restrict__ out, int Nn) {
    int n = (blockIdx.x * 256 + threadIdx.x) >> 6;
    int lane = threadIdx.x & 63;
    if (n >= Nn) return;
    int beg = rp[n], end = rp[n + 1];
    float acc = 0.f;
    int j = beg;
    for (; j + 1 < end; j += 2) {
        int s0 = csr[j], s1 = csr[j + 1];
        float w0 = dis[s0], w1 = dis[s1];
        float v0 = h[(size_t)s0 * 64 + lane];
        float v1 = h[(size_t)s1 * 64 + lane];
        acc = fmaf(w0, v0, acc);
        acc = fmaf(w1, v1, acc);
    }
    if (j < end) {
        int s = csr[j];
        acc = fmaf(dis[s], h[(size_t)s * 64 + lane], acc);
    }
    float dn = dis[n];
    float hv = h[(size_t)n * 64 + lane];
    out[(size_t)n * 64 + lane] = dn * (acc + dn * hv) + bias[lane];
}

extern "C" void kernel_launch(void* const* d_in, const int* in_sizes, int n_in,
                              void* d_out, int out_size, void* d_ws, size_t ws_size,
                              hipStream_t stream) {
    const float* x  = (const float*)d_in[0];
    const int*   ei = (const int*)d_in[1];
    const float* W1 = (const float*)d_in[2];
    const float* b1 = (const float*)d_in[3];
    const float* W2 = (const float*)d_in[4];
    const float* b2 = (const float*)d_in[5];

    const int IN = 500, H = 128, OUT = 64;
    const int Nn = in_sizes[0] / IN;     // 50000
    const int E  = in_sizes[1] / 2;      // 800000
    const int* src  = ei;
    const int* dstp = ei + E;

    const int Npad = ((Nn + 63) / 64) * 64;

    // workspace layout
    int*   degdis  = (int*)d_ws;             // N ints -> becomes float dis in place
    int*   rp      = degdis + Npad;          // N+1
    int*   cursor  = rp + Npad + 64;         // N
    int*   csr_src = cursor + Npad;          // E
    float* h1      = (float*)(csr_src + ((E + 63) / 64) * 64);  // N*128
    float* agg1    = h1 + (size_t)Nn * H;    // N*128
    float* h2      = h1;                     // reuse after layer-1 gather
    float* dis     = (float*)degdis;
    float* out     = (float*)d_out;

    // ---- degree / CSR build ----
    fill_int<<<(Nn + 255) / 256, 256, 0, stream>>>(degdis, 0, Nn);
    deg_accum_i<<<(E + 255) / 256, 256, 0, stream>>>(dstp, degdis, E);
    scan_block<<<1, 1024, 0, stream>>>(degdis, rp, Nn);
    make_dis<<<(Nn + 255) / 256, 256, 0, stream>>>(degdis, Nn);
    copy_int<<<(Nn + 255) / 256, 256, 0, stream>>>(rp, cursor, Nn);
    csr_fill<<<(E + 255) / 256, 256, 0, stream>>>(src, dstp, cursor, csr_src, E);

    // ---- layer 1 ----
    gemm_f32<64, 128, 10, 4, 8><<<(Nn + 63) / 64, 256, 0, stream>>>(x, W1, h1, Nn, IN);
    gather128<<<(Nn + 3) / 4, 256, 0, stream>>>(rp, csr_src, dis, h1, b1, agg1, Nn);

    // ---- layer 2 ----
    gemm_f32<64, 64, 16, 4, 4><<<(Nn + 63) / 64, 256, 0, stream>>>(agg1, W2, h2, Nn, H);
    gather64<<<(Nn + 3) / 4, 256, 0, stream>>>(rp, csr_src, dis, h2, b2, out, Nn);
}

// Round 3
// 341.666 us; speedup vs baseline: 3.2317x; 1.3617x over previous
//
#include <hip/hip_runtime.h>
#include <hip/hip_bf16.h>

// GCN 2-layer encoder. CSR-gather aggregation + split-bf16 MFMA GEMMs.
// Layer: h = x@W ; out[n] = dis[n]*(sum_{e:dst=n} dis[src]*h[src] + dis[n]*h[n]) + b ; relu (layer1)

typedef __attribute__((ext_vector_type(4))) float f32x4;
typedef __attribute__((ext_vector_type(8))) short short8;

static __device__ __forceinline__ unsigned short f2bf(float f) {
    unsigned int u = __float_as_uint(f);
    u += 0x7FFF + ((u >> 16) & 1);          // round-to-nearest-even
    return (unsigned short)(u >> 16);
}
static __device__ __forceinline__ float bf2f(unsigned short h) {
    return __uint_as_float(((unsigned int)h) << 16);
}

__global__ void fill_int(int* __restrict__ p, int v, int n) {
    int i = blockIdx.x * blockDim.x + threadIdx.x;
    if (i < n) p[i] = v;
}

__global__ void deg_accum_i(const int* __restrict__ dst, int* __restrict__ deg, int E) {
    int i = blockIdx.x * blockDim.x + threadIdx.x;
    if (i < E) atomicAdd(&deg[dst[i]], 1);
}

__global__ void make_dis(int* __restrict__ deg, int N) {
    int i = blockIdx.x * blockDim.x + threadIdx.x;
    if (i < N) {
        int d = deg[i];
        ((float*)deg)[i] = rsqrtf((float)(d + 1));
    }
}

__global__ __launch_bounds__(1024) void scan_block(const int* __restrict__ deg, int* __restrict__ rp, int N) {
    __shared__ int wsum[16];
    __shared__ int carry_s;
    const int tid = threadIdx.x;
    const int lane = tid & 63;
    const int wid = tid >> 6;
    if (tid == 0) carry_s = 0;
    __syncthreads();
    for (int start = 0; start < N; start += 1024) {
        int i = start + tid;
        int v = (i < N) ? deg[i] : 0;
        int x = v;
#pragma unroll
        for (int off = 1; off < 64; off <<= 1) {
            int t = __shfl_up(x, off, 64);
            if (lane >= off) x += t;
        }
        if (lane == 63) wsum[wid] = x;
        __syncthreads();
        if (tid < 16) {
            int y = wsum[tid];
#pragma unroll
            for (int off = 1; off < 16; off <<= 1) {
                int t = __shfl_up(y, off, 16);
                if (tid >= off) y += t;
            }
            wsum[tid] = y;
        }
        __syncthreads();
        int base = carry_s + (wid ? wsum[wid - 1] : 0);
        if (i < N) rp[i] = base + x - v;  // exclusive
        __syncthreads();
        if (tid == 0) carry_s += wsum[15];
        __syncthreads();
    }
    if (tid == 0) rp[N] = carry_s;
}

__global__ void copy_int(const int* __restrict__ a, int* __restrict__ b, int n) {
    int i = blockIdx.x * blockDim.x + threadIdx.x;
    if (i < n) b[i] = a[i];
}

__global__ void csr_fill(const int* __restrict__ src, const int* __restrict__ dst,
                         int* __restrict__ cursor, int* __restrict__ csr_src, int E) {
    int e = blockIdx.x * blockDim.x + threadIdx.x;
    if (e < E) {
        int pos = atomicAdd(&cursor[dst[e]], 1);
        csr_src[pos] = src[e];
    }
}

// C[M x BN] = A[M x K] @ B[K x BN] via split-bf16 MFMA (A,B f32 in, f32 out).
// BM=128, BK=32, 256 threads = 4 waves arranged WROWS x WCOLS.
template<int BN, int WROWS, int WCOLS>
__global__ __launch_bounds__(256) void gemm_mfma(
    const float* __restrict__ A, const float* __restrict__ B,
    float* __restrict__ C, int M, int K) {
    constexpr int BM = 128, BK = 32, STR = 40;   // STR breaks pow2 banks, keeps b128 align
    constexpr int MF = (BM / WROWS) / 16;
    constexpr int NF = (BN / WCOLS) / 16;
    constexpr int CH = BN / 8;                   // B elems per thread (along k)
    static_assert(BK * BN / 256 == CH, "B staging mapping");

    __shared__ unsigned short AsH[BM][STR], AsL[BM][STR];
    __shared__ unsigned short BsH[BN][STR], BsL[BN][STR];

    const int tid  = threadIdx.x;
    const int lane = tid & 63;
    const int w    = tid >> 6;
    const int wrow = (w / WCOLS) * (BM / WROWS);
    const int wcol = (w % WCOLS) * (BN / WCOLS);
    const int bm   = blockIdx.x * BM;
    const int lrow = lane & 15;
    const int lk   = (lane >> 4) * 8;
    const int bcol   = tid % BN;
    const int bkbase = (tid / BN) * CH;

    f32x4 acc[MF][NF] = {};

    const int nk = (K + BK - 1) / BK;
    for (int kt = 0; kt < nk; kt++) {
        const int k0 = kt * BK;
        // ---- stage A tile: 128 rows x 32 k, f32 -> bf16 hi/lo ----
#pragma unroll
        for (int i = 0; i < 4; i++) {
            int slot = tid + 256 * i;            // 0..1023 = 128 rows x 8 float4
            int r = slot >> 3, kk = (slot & 7) * 4;
            int row = bm + r, kg = k0 + kk;
            float4 v = make_float4(0.f, 0.f, 0.f, 0.f);
            if (row < M) {
                if (kg + 3 < K) v = *(const float4*)&A[(size_t)row * K + kg];
                else {
                    if (kg + 0 < K) v.x = A[(size_t)row * K + kg + 0];
                    if (kg + 1 < K) v.y = A[(size_t)row * K + kg + 1];
                    if (kg + 2 < K) v.z = A[(size_t)row * K + kg + 2];
                    if (kg + 3 < K) v.w = A[(size_t)row * K + kg + 3];
                }
            }
            ushort4 h4, l4;
            h4.x = f2bf(v.x); l4.x = f2bf(v.x - bf2f(h4.x));
            h4.y = f2bf(v.y); l4.y = f2bf(v.y - bf2f(h4.y));
            h4.z = f2bf(v.z); l4.z = f2bf(v.z - bf2f(h4.z));
            h4.w = f2bf(v.w); l4.w = f2bf(v.w - bf2f(h4.w));
            *(ushort4*)&AsH[r][kk] = h4;
            *(ushort4*)&AsL[r][kk] = l4;
        }
        // ---- stage B tile: 32 k x BN, f32 -> bf16 hi/lo, stored transposed [col][k] ----
        {
            float vv[CH];
#pragma unroll
            for (int i = 0; i < CH; i++) {
                int kg = k0 + bkbase + i;
                vv[i] = (kg < K) ? B[(size_t)kg * BN + bcol] : 0.f;
            }
#pragma unroll
            for (int g = 0; g < CH / 4; g++) {
                ushort4 h4, l4;
                float a0 = vv[g * 4 + 0], a1 = vv[g * 4 + 1], a2 = vv[g * 4 + 2], a3 = vv[g * 4 + 3];
                h4.x = f2bf(a0); l4.x = f2bf(a0 - bf2f(h4.x));
                h4.y = f2bf(a1); l4.y = f2bf(a1 - bf2f(h4.y));
                h4.z = f2bf(a2); l4.z = f2bf(a2 - bf2f(h4.z));
                h4.w = f2bf(a3); l4.w = f2bf(a3 - bf2f(h4.w));
                *(ushort4*)&BsH[bcol][bkbase + g * 4] = h4;
                *(ushort4*)&BsL[bcol][bkbase + g * 4] = l4;
            }
        }
        __syncthreads();
        // ---- fragments + MFMA (one 16x16x32 K-step per tile) ----
        short8 ah[MF], al[MF], bh[NF], bl[NF];
#pragma unroll
        for (int m = 0; m < MF; m++) {
            ah[m] = *(const short8*)&AsH[wrow + m * 16 + lrow][lk];
            al[m] = *(const short8*)&AsL[wrow + m * 16 + lrow][lk];
        }
#pragma unroll
        for (int n = 0; n < NF; n++) {
            bh[n] = *(const short8*)&BsH[wcol + n * 16 + lrow][lk];
            bl[n] = *(const short8*)&BsL[wcol + n * 16 + lrow][lk];
        }
#pragma unroll
        for (int m = 0; m < MF; m++)
#pragma unroll
            for (int n = 0; n < NF; n++) {
                acc[m][n] = __builtin_amdgcn_mfma_f32_16x16x32_bf16(ah[m], bh[n], acc[m][n], 0, 0, 0);
                acc[m][n] = __builtin_amdgcn_mfma_f32_16x16x32_bf16(al[m], bh[n], acc[m][n], 0, 0, 0);
                acc[m][n] = __builtin_amdgcn_mfma_f32_16x16x32_bf16(ah[m], bl[n], acc[m][n], 0, 0, 0);
            }
        __syncthreads();
    }
    // ---- store: C/D layout col=lane&15, row=(lane>>4)*4+q ----
#pragma unroll
    for (int m = 0; m < MF; m++)
#pragma unroll
        for (int n = 0; n < NF; n++)
#pragma unroll
            for (int q = 0; q < 4; q++) {
                int row = bm + wrow + m * 16 + (lane >> 4) * 4 + q;
                int col = wcol + n * 16 + (lane & 15);
                if (row < M) C[(size_t)row * BN + col] = acc[m][n][q];
            }
}

// one wave per dst node, lanes across 128 features (float2/lane); fused self-loop+bias+relu
__global__ __launch_bounds__(256) void gather128(
    const int* __restrict__ rp, const int* __restrict__ csr,
    const float* __restrict__ dis, const float* __restrict__ h,
    const float* __restrict__ bias, float* __restrict__ out, int Nn) {
    int n = (blockIdx.x * 256 + threadIdx.x) >> 6;
    int lane = threadIdx.x & 63;
    if (n >= Nn) return;
    int beg = rp[n], end = rp[n + 1];
    float accx = 0.f, accy = 0.f;
    int j = beg;
    for (; j + 1 < end; j += 2) {
        int s0 = csr[j], s1 = csr[j + 1];
        float w0 = dis[s0], w1 = dis[s1];
        float2 v0 = *(const float2*)&h[(size_t)s0 * 128 + lane * 2];
        float2 v1 = *(const float2*)&h[(size_t)s1 * 128 + lane * 2];
        accx = fmaf(w0, v0.x, accx); accy = fmaf(w0, v0.y, accy);
        accx = fmaf(w1, v1.x, accx); accy = fmaf(w1, v1.y, accy);
    }
    if (j < end) {
        int s = csr[j];
        float w = dis[s];
        float2 v = *(const float2*)&h[(size_t)s * 128 + lane * 2];
        accx = fmaf(w, v.x, accx); accy = fmaf(w, v.y, accy);
    }
    float dn = dis[n];
    float2 hv = *(const float2*)&h[(size_t)n * 128 + lane * 2];
    float2 o;
    o.x = fmaxf(dn * (accx + dn * hv.x) + bias[lane * 2], 0.f);
    o.y = fmaxf(dn * (accy + dn * hv.y) + bias[lane * 2 + 1], 0.f);
    *(float2*)&out[(size_t)n * 128 + lane * 2] = o;
}

// one wave per dst node, lanes across 64 features; fused self-loop+bias (no relu)
__global__ __launch_bounds__(256) void gather64(
    const int* __restrict__ rp, const int* __restrict__ csr,
    const float* __restrict__ dis, const float* __restrict__ h,
    const float* __restrict__ bias, float* __restrict__ out, int Nn) {
    int n = (blockIdx.x * 256 + threadIdx.x) >> 6;
    int lane = threadIdx.x & 63;
    if (n >= Nn) return;
    int beg = rp[n], end = rp[n + 1];
    float acc = 0.f;
    int j = beg;
    for (; j + 1 < end; j += 2) {
        int s0 = csr[j], s1 = csr[j + 1];
        float w0 = dis[s0], w1 = dis[s1];
        float v0 = h[(size_t)s0 * 64 + lane];
        float v1 = h[(size_t)s1 * 64 + lane];
        acc = fmaf(w0, v0, acc);
        acc = fmaf(w1, v1, acc);
    }
    if (j < end) {
        int s = csr[j];
        acc = fmaf(dis[s], h[(size_t)s * 64 + lane], acc);
    }
    float dn = dis[n];
    float hv = h[(size_t)n * 64 + lane];
    out[(size_t)n * 64 + lane] = dn * (acc + dn * hv) + bias[lane];
}

extern "C" void kernel_launch(void* const* d_in, const int* in_sizes, int n_in,
                              void* d_out, int out_size, void* d_ws, size_t ws_size,
                              hipStream_t stream) {
    const float* x  = (const float*)d_in[0];
    const int*   ei = (const int*)d_in[1];
    const float* W1 = (const float*)d_in[2];
    const float* b1 = (const float*)d_in[3];
    const float* W2 = (const float*)d_in[4];
    const float* b2 = (const float*)d_in[5];

    const int IN = 500, H = 128, OUT = 64;
    const int Nn = in_sizes[0] / IN;     // 50000
    const int E  = in_sizes[1] / 2;      // 800000
    const int* src  = ei;
    const int* dstp = ei + E;

    const int Npad = ((Nn + 63) / 64) * 64;

    // workspace layout
    int*   degdis  = (int*)d_ws;             // N ints -> becomes float dis in place
    int*   rp      = degdis + Npad;          // N+1
    int*   cursor  = rp + Npad + 64;         // N
    int*   csr_src = cursor + Npad;          // E
    float* h1      = (float*)(csr_src + ((E + 63) / 64) * 64);  // N*128
    float* agg1    = h1 + (size_t)Nn * H;    // N*128
    float* h2      = h1;                     // reuse after layer-1 gather
    float* dis     = (float*)degdis;
    float* out     = (float*)d_out;

    // ---- degree / CSR build ----
    fill_int<<<(Nn + 255) / 256, 256, 0, stream>>>(degdis, 0, Nn);
    deg_accum_i<<<(E + 255) / 256, 256, 0, stream>>>(dstp, degdis, E);
    scan_block<<<1, 1024, 0, stream>>>(degdis, rp, Nn);
    make_dis<<<(Nn + 255) / 256, 256, 0, stream>>>(degdis, Nn);
    copy_int<<<(Nn + 255) / 256, 256, 0, stream>>>(rp, cursor, Nn);
    csr_fill<<<(E + 255) / 256, 256, 0, stream>>>(src, dstp, cursor, csr_src, E);

    // ---- layer 1: h1 = x @ W1 (MFMA), then gather ----
    gemm_mfma<128, 2, 2><<<(Nn + 127) / 128, 256, 0, stream>>>(x, W1, h1, Nn, IN);
    gather128<<<(Nn + 3) / 4, 256, 0, stream>>>(rp, csr_src, dis, h1, b1, agg1, Nn);

    // ---- layer 2: h2 = agg1 @ W2 (MFMA), then gather ----
    gemm_mfma<64, 4, 1><<<(Nn + 127) / 128, 256, 0, stream>>>(agg1, W2, h2, Nn, H);
    gather64<<<(Nn + 3) / 4, 256, 0, stream>>>(rp, csr_src, dis, h2, b2, out, Nn);
}

// Round 5
// 266.707 us; speedup vs baseline: 4.1399x; 1.2811x over previous
//
#include <hip/hip_runtime.h>
#include <hip/hip_bf16.h>

// GCN 2-layer encoder. CSR-gather aggregation + split-bf16 MFMA GEMMs.
// Layer: h = x@W ; out[n] = dis[n]*(sum_{e:dst=n} dis[src]*h[src] + dis[n]*h[n]) + b ; relu (layer1)

typedef __attribute__((ext_vector_type(4))) float f32x4;
typedef __attribute__((ext_vector_type(8))) short short8;
typedef __attribute__((ext_vector_type(8))) unsigned short u16x8;

static __device__ __forceinline__ unsigned short f2bf(float f) {
    unsigned int u = __float_as_uint(f);
    u += 0x7FFF + ((u >> 16) & 1);          // round-to-nearest-even
    return (unsigned short)(u >> 16);
}
static __device__ __forceinline__ float bf2f(unsigned short h) {
    return __uint_as_float(((unsigned int)h) << 16);
}

__global__ void fill_int(int* __restrict__ p, int v, int n) {
    int i = blockIdx.x * blockDim.x + threadIdx.x;
    if (i < n) p[i] = v;
}

__global__ void deg_accum_i(const int* __restrict__ dst, int* __restrict__ deg, int E) {
    int i = blockIdx.x * blockDim.x + threadIdx.x;
    if (i < E) atomicAdd(&deg[dst[i]], 1);
}

__global__ void make_dis(int* __restrict__ deg, int N) {
    int i = blockIdx.x * blockDim.x + threadIdx.x;
    if (i < N) {
        int d = deg[i];
        ((float*)deg)[i] = rsqrtf((float)(d + 1));
    }
}

// ---- hierarchical exclusive scan: deg[N] -> rp[N+1], cursor[N] ----
__global__ void scan_part(const int* __restrict__ deg, int* __restrict__ bsum, int N) {
    int tid = threadIdx.x, lane = tid & 63, wid = tid >> 6;
    int i = blockIdx.x * 256 + tid;
    int v = (i < N) ? deg[i] : 0;
#pragma unroll
    for (int off = 1; off < 64; off <<= 1) v += __shfl_xor(v, off, 64);
    __shared__ int ws[4];
    if (lane == 0) ws[wid] = v;
    __syncthreads();
    if (tid == 0) bsum[blockIdx.x] = ws[0] + ws[1] + ws[2] + ws[3];
}

__global__ __launch_bounds__(1024) void scan_top(const int* __restrict__ bsum, int nb,
                                                 int* __restrict__ boff, int* __restrict__ rp, int N) {
    __shared__ int wsum[16];
    int tid = threadIdx.x, lane = tid & 63, wid = tid >> 6;
    int v = (tid < nb) ? bsum[tid] : 0;
    int x = v;
#pragma unroll
    for (int off = 1; off < 64; off <<= 1) {
        int t = __shfl_up(x, off, 64);
        if (lane >= off) x += t;
    }
    if (lane == 63) wsum[wid] = x;
    __syncthreads();
    if (tid < 16) {
        int y = wsum[tid];
#pragma unroll
        for (int off = 1; off < 16; off <<= 1) {
            int t = __shfl_up(y, off, 16);
            if (tid >= off) y += t;
        }
        wsum[tid] = y;
    }
    __syncthreads();
    int base = wid ? wsum[wid - 1] : 0;
    if (tid < nb) boff[tid] = base + x - v;
    if (tid == 0) rp[N] = wsum[15];
}

__global__ void scan_final(const int* __restrict__ deg, const int* __restrict__ boff,
                           int* __restrict__ rp, int* __restrict__ cursor, int N) {
    int tid = threadIdx.x, lane = tid & 63, wid = tid >> 6;
    int i = blockIdx.x * 256 + tid;
    int v = (i < N) ? deg[i] : 0;
    int x = v;
#pragma unroll
    for (int off = 1; off < 64; off <<= 1) {
        int t = __shfl_up(x, off, 64);
        if (lane >= off) x += t;
    }
    __shared__ int wsum[4];
    if (lane == 63) wsum[wid] = x;
    __syncthreads();
    int base = boff[blockIdx.x];
    for (int ww = 0; ww < wid; ww++) base += wsum[ww];
    int ex = base + x - v;
    if (i < N) { rp[i] = ex; cursor[i] = ex; }
}

__global__ void csr_fill(const int* __restrict__ src, const int* __restrict__ dst,
                         int* __restrict__ cursor, int* __restrict__ csr_src, int E) {
    int e = blockIdx.x * blockDim.x + threadIdx.x;
    if (e < E) {
        int pos = atomicAdd(&cursor[dst[e]], 1);
        csr_src[pos] = src[e];
    }
}

// B[K x N] f32 -> transposed bf16 hi/lo [N][Kpad] (zero-padded past K)
__global__ void prep_b(const float* __restrict__ B, unsigned short* __restrict__ Bth,
                       unsigned short* __restrict__ Btl, int K, int N, int Kpad) {
    int idx = blockIdx.x * 256 + threadIdx.x;
    if (idx >= N * Kpad) return;
    int n = idx / Kpad, k = idx - n * Kpad;
    float v = (k < K) ? B[(size_t)k * N + n] : 0.f;
    unsigned short h = f2bf(v);
    Bth[idx] = h;
    Btl[idx] = f2bf(v - bf2f(h));
}

// C[M x BN] = A[M x K] @ B[K x BN], split-bf16 MFMA. A f32, B preconverted bf16 hi/lo [BN][Kpad].
// 256 threads = 4 waves (WROWS x WCOLS). Reg-staged prefetch pipeline.
template<int BM, int BN, int BK, int WROWS, int WCOLS>
__global__ __launch_bounds__(256) void gemm_mfma(
    const float* __restrict__ A, const unsigned short* __restrict__ Bth,
    const unsigned short* __restrict__ Btl, float* __restrict__ C,
    int M, int K, int Kpad) {
    constexpr int STR = BK + 8;                  // LDS row stride (ushorts): breaks pow2 banks, 16B-aligned
    constexpr int MF = (BM / WROWS) / 16;
    constexpr int NF = (BN / WCOLS) / 16;
    constexpr int KS = BK / 32;
    constexpr int ALOOP = (BM * BK) / (4 * 256); // float4 slots per thread
    constexpr int TPRA = BK / 4;                 // threads per A row
    constexpr int TPNB = BK / 16;                // threads per B n-row (16-ushort chunks)
    static_assert(BN * TPNB == 256, "B staging: one 16-ushort chunk per thread");

    __shared__ unsigned short AsH[BM][STR], AsL[BM][STR];
    __shared__ unsigned short BsH[BN][STR], BsL[BN][STR];

    const int tid = threadIdx.x;
    const int lane = tid & 63;
    const int w = tid >> 6;
    const int wrow = (w / WCOLS) * (BM / WROWS);
    const int wcol = (w % WCOLS) * (BN / WCOLS);
    const int bm = blockIdx.x * BM;
    const int lrow = lane & 15;
    const int lkq = (lane >> 4) * 8;
    const int bn = tid / TPNB;
    const int bkoff = (tid % TPNB) * 16;

    f32x4 acc[MF][NF] = {};
    float4 areg[ALOOP];
    u16x8 bh0, bh1, bl0, bl1;

    const int nk = (K + BK - 1) / BK;

    auto loadTile = [&](int kt) {
        const int k0 = kt * BK;
#pragma unroll
        for (int i = 0; i < ALOOP; i++) {
            int slot = tid + 256 * i;
            int r = slot / TPRA;
            int kk = (slot % TPRA) * 4;
            int row = bm + r, kg = k0 + kk;
            float4 v = make_float4(0.f, 0.f, 0.f, 0.f);
            if (row < M) {
                const float* p = &A[(size_t)row * K + kg];
                if (kg + 3 < K) v = *(const float4*)p;
                else {
                    if (kg     < K) v.x = p[0];
                    if (kg + 1 < K) v.y = p[1];
                    if (kg + 2 < K) v.z = p[2];
                }
            }
            areg[i] = v;
        }
        const size_t bo = (size_t)bn * Kpad + k0 + bkoff;
        bh0 = *(const u16x8*)&Bth[bo];
        bh1 = *(const u16x8*)&Bth[bo + 8];
        bl0 = *(const u16x8*)&Btl[bo];
        bl1 = *(const u16x8*)&Btl[bo + 8];
    };
    auto writeTile = [&]() {
#pragma unroll
        for (int i = 0; i < ALOOP; i++) {
            int slot = tid + 256 * i;
            int r = slot / TPRA;
            int kk = (slot % TPRA) * 4;
            float4 v = areg[i];
            ushort4 h4, l4;
            h4.x = f2bf(v.x); l4.x = f2bf(v.x - bf2f(h4.x));
            h4.y = f2bf(v.y); l4.y = f2bf(v.y - bf2f(h4.y));
            h4.z = f2bf(v.z); l4.z = f2bf(v.z - bf2f(h4.z));
            h4.w = f2bf(v.w); l4.w = f2bf(v.w - bf2f(h4.w));
            *(ushort4*)&AsH[r][kk] = h4;
            *(ushort4*)&AsL[r][kk] = l4;
        }
        *(u16x8*)&BsH[bn][bkoff]     = bh0;
        *(u16x8*)&BsH[bn][bkoff + 8] = bh1;
        *(u16x8*)&BsL[bn][bkoff]     = bl0;
        *(u16x8*)&BsL[bn][bkoff + 8] = bl1;
    };

    loadTile(0);
    for (int kt = 0; kt < nk; kt++) {
        writeTile();
        __syncthreads();
        if (kt + 1 < nk) loadTile(kt + 1);   // global loads in flight during MFMA below
        short8 ah[MF][KS], al[MF][KS], bhf[NF][KS], blf[NF][KS];
#pragma unroll
        for (int ks = 0; ks < KS; ks++) {
            const int ko = ks * 32 + lkq;
#pragma unroll
            for (int m = 0; m < MF; m++) {
                ah[m][ks] = *(const short8*)&AsH[wrow + m * 16 + lrow][ko];
                al[m][ks] = *(const short8*)&AsL[wrow + m * 16 + lrow][ko];
            }
#pragma unroll
            for (int n = 0; n < NF; n++) {
                bhf[n][ks] = *(const short8*)&BsH[wcol + n * 16 + lrow][ko];
                blf[n][ks] = *(const short8*)&BsL[wcol + n * 16 + lrow][ko];
            }
        }
#pragma unroll
        for (int ks = 0; ks < KS; ks++)
#pragma unroll
            for (int m = 0; m < MF; m++)
#pragma unroll
                for (int n = 0; n < NF; n++) {
                    acc[m][n] = __builtin_amdgcn_mfma_f32_16x16x32_bf16(ah[m][ks], bhf[n][ks], acc[m][n], 0, 0, 0);
                    acc[m][n] = __builtin_amdgcn_mfma_f32_16x16x32_bf16(al[m][ks], bhf[n][ks], acc[m][n], 0, 0, 0);
                    acc[m][n] = __builtin_amdgcn_mfma_f32_16x16x32_bf16(ah[m][ks], blf[n][ks], acc[m][n], 0, 0, 0);
                }
        __syncthreads();
    }
    // store: C/D layout col=lane&15, row=(lane>>4)*4+q
#pragma unroll
    for (int m = 0; m < MF; m++)
#pragma unroll
        for (int n = 0; n < NF; n++)
#pragma unroll
            for (int q = 0; q < 4; q++) {
                int row = bm + wrow + m * 16 + (lane >> 4) * 4 + q;
                int col = wcol + n * 16 + (lane & 15);
                if (row < M) C[(size_t)row * BN + col] = acc[m][n][q];
            }
}

// one wave per dst node, lanes across 128 features (float2/lane); fused self-loop+bias+relu
__global__ __launch_bounds__(256) void gather128(
    const int* __restrict__ rp, const int* __restrict__ csr,
    const float* __restrict__ dis, const float* __restrict__ h,
    const float* __restrict__ bias, float* __restrict__ out, int Nn) {
    int n = (blockIdx.x * 256 + threadIdx.x) >> 6;
    int lane = threadIdx.x & 63;
    if (n >= Nn) return;
    int beg = rp[n], end = rp[n + 1];
    float a0x = 0.f, a0y = 0.f, a1x = 0.f, a1y = 0.f;
    float a2x = 0.f, a2y = 0.f, a3x = 0.f, a3y = 0.f;
    int j = beg;
    for (; j + 3 < end; j += 4) {
        int s0 = csr[j], s1 = csr[j + 1], s2 = csr[j + 2], s3 = csr[j + 3];
        float w0 = dis[s0], w1 = dis[s1], w2 = dis[s2], w3 = dis[s3];
        float2 v0 = *(const float2*)&h[(size_t)s0 * 128 + lane * 2];
        float2 v1 = *(const float2*)&h[(size_t)s1 * 128 + lane * 2];
        float2 v2 = *(const float2*)&h[(size_t)s2 * 128 + lane * 2];
        float2 v3 = *(const float2*)&h[(size_t)s3 * 128 + lane * 2];
        a0x = fmaf(w0, v0.x, a0x); a0y = fmaf(w0, v0.y, a0y);
        a1x = fmaf(w1, v1.x, a1x); a1y = fmaf(w1, v1.y, a1y);
        a2x = fmaf(w2, v2.x, a2x); a2y = fmaf(w2, v2.y, a2y);
        a3x = fmaf(w3, v3.x, a3x); a3y = fmaf(w3, v3.y, a3y);
    }
    for (; j < end; j++) {
        int s = csr[j];
        float ww = dis[s];
        float2 v = *(const float2*)&h[(size_t)s * 128 + lane * 2];
        a0x = fmaf(ww, v.x, a0x); a0y = fmaf(ww, v.y, a0y);
    }
    float accx = (a0x + a1x) + (a2x + a3x);
    float accy = (a0y + a1y) + (a2y + a3y);
    float dn = dis[n];
    float2 hv = *(const float2*)&h[(size_t)n * 128 + lane * 2];
    float2 o;
    o.x = fmaxf(dn * (accx + dn * hv.x) + bias[lane * 2], 0.f);
    o.y = fmaxf(dn * (accy + dn * hv.y) + bias[lane * 2 + 1], 0.f);
    *(float2*)&out[(size_t)n * 128 + lane * 2] = o;
}

// one wave per dst node, lanes across 64 features; fused self-loop+bias (no relu)
__global__ __launch_bounds__(256) void gather64(
    const int* __restrict__ rp, const int* __restrict__ csr,
    const float* __restrict__ dis, const float* __restrict__ h,
    const float* __restrict__ bias, float* __restrict__ out, int Nn) {
    int n = (blockIdx.x * 256 + threadIdx.x) >> 6;
    int lane = threadIdx.x & 63;
    if (n >= Nn) return;
    int beg = rp[n], end = rp[n + 1];
    float a0 = 0.f, a1 = 0.f, a2 = 0.f, a3 = 0.f;
    int j = beg;
    for (; j + 3 < end; j += 4) {
        int s0 = csr[j], s1 = csr[j + 1], s2 = csr[j + 2], s3 = csr[j + 3];
        float w0 = dis[s0], w1 = dis[s1], w2 = dis[s2], w3 = dis[s3];
        float v0 = h[(size_t)s0 * 64 + lane];
        float v1 = h[(size_t)s1 * 64 + lane];
        float v2 = h[(size_t)s2 * 64 + lane];
        float v3 = h[(size_t)s3 * 64 + lane];
        a0 = fmaf(w0, v0, a0); a1 = fmaf(w1, v1, a1);
        a2 = fmaf(w2, v2, a2); a3 = fmaf(w3, v3, a3);
    }
    for (; j < end; j++) {
        int s = csr[j];
        a0 = fmaf(dis[s], h[(size_t)s * 64 + lane], a0);
    }
    float acc = (a0 + a1) + (a2 + a3);
    float dn = dis[n];
    float hv = h[(size_t)n * 64 + lane];
    out[(size_t)n * 64 + lane] = dn * (acc + dn * hv) + bias[lane];
}

extern "C" void kernel_launch(void* const* d_in, const int* in_sizes, int n_in,
                              void* d_out, int out_size, void* d_ws, size_t ws_size,
                              hipStream_t stream) {
    const float* x  = (const float*)d_in[0];
    const int*   ei = (const int*)d_in[1];
    const float* W1 = (const float*)d_in[2];
    const float* b1 = (const float*)d_in[3];
    const float* W2 = (const float*)d_in[4];
    const float* b2 = (const float*)d_in[5];

    const int IN = 500, H = 128, OUT = 64;
    const int Nn = in_sizes[0] / IN;     // 50000
    const int E  = in_sizes[1] / 2;      // 800000
    const int* src  = ei;
    const int* dstp = ei + E;

    const int Npad = ((Nn + 63) / 64) * 64;
    const int nb   = (Nn + 255) / 256;
    const int K1p  = 512, K2p = 128;

    // workspace layout (int units)
    int*   degdis  = (int*)d_ws;                 // N: int deg -> float dis in place
    int*   rp      = degdis + Npad;              // N+1
    int*   bsum    = rp + Npad + 64;             // 1024
    int*   boff    = bsum + 1024;                // 1024
    int*   cursor  = boff + 1024;                // N
    int*   csr_src = cursor + Npad;              // E
    unsigned short* Bt1h = (unsigned short*)(csr_src + ((E + 63) / 64) * 64);  // 128*512
    unsigned short* Bt1l = Bt1h + H * K1p;
    unsigned short* Bt2h = Bt1l + H * K1p;       // 64*128
    unsigned short* Bt2l = Bt2h + OUT * K2p;
    float* h1      = (float*)(Bt2l + OUT * K2p);
    float* agg1    = h1 + (size_t)Nn * H;
    float* h2      = h1;                         // reuse after layer-1 gather
    float* dis     = (float*)degdis;
    float* out     = (float*)d_out;

    // ---- degree / CSR build ----
    fill_int<<<(Nn + 255) / 256, 256, 0, stream>>>(degdis, 0, Nn);
    deg_accum_i<<<(E + 255) / 256, 256, 0, stream>>>(dstp, degdis, E);
    scan_part<<<nb, 256, 0, stream>>>(degdis, bsum, Nn);
    scan_top<<<1, 1024, 0, stream>>>(bsum, nb, boff, rp, Nn);
    scan_final<<<nb, 256, 0, stream>>>(degdis, boff, rp, cursor, Nn);
    make_dis<<<(Nn + 255) / 256, 256, 0, stream>>>(degdis, Nn);
    csr_fill<<<(E + 255) / 256, 256, 0, stream>>>(src, dstp, cursor, csr_src, E);

    // ---- weight prep (bf16 hi/lo, transposed) ----
    prep_b<<<(H * K1p + 255) / 256, 256, 0, stream>>>(W1, Bt1h, Bt1l, IN, H, K1p);
    prep_b<<<(OUT * K2p + 255) / 256, 256, 0, stream>>>(W2, Bt2h, Bt2l, H, OUT, K2p);

    // ---- layer 1 ----
    gemm_mfma<32, 128, 32, 2, 2><<<(Nn + 31) / 32, 256, 0, stream>>>(x, Bt1h, Bt1l, h1, Nn, IN, K1p);
    gather128<<<(Nn + 3) / 4, 256, 0, stream>>>(rp, csr_src, dis, h1, b1, agg1, Nn);

    // ---- layer 2 ----
    gemm_mfma<32, 64, 64, 2, 2><<<(Nn + 31) / 32, 256, 0, stream>>>(agg1, Bt2h, Bt2l, h2, Nn, H, K2p);
    gather64<<<(Nn + 3) / 4, 256, 0, stream>>>(rp, csr_src, dis, h2, b2, out, Nn);
}

// Round 6
// 263.489 us; speedup vs baseline: 4.1905x; 1.0122x over previous
//
#include <hip/hip_runtime.h>
#include <hip/hip_bf16.h>

// GCN 2-layer encoder. CSR-gather aggregation + split-bf16 MFMA GEMMs.
// GEMM: A fully register-preloaded (one HBM drain per block), B (weights) L2-resident per-tile prefetch.

typedef __attribute__((ext_vector_type(4))) float f32x4;
typedef __attribute__((ext_vector_type(8))) short short8;
typedef __attribute__((ext_vector_type(8))) unsigned short u16x8;

static __device__ __forceinline__ unsigned short f2bf(float f) {
    unsigned int u = __float_as_uint(f);
    u += 0x7FFF + ((u >> 16) & 1);          // round-to-nearest-even
    return (unsigned short)(u >> 16);
}
static __device__ __forceinline__ float bf2f(unsigned short h) {
    return __uint_as_float(((unsigned int)h) << 16);
}

__global__ void fill_int(int* __restrict__ p, int v, int n) {
    int i = blockIdx.x * blockDim.x + threadIdx.x;
    if (i < n) p[i] = v;
}

__global__ void deg_accum_i(const int* __restrict__ dst, int* __restrict__ deg, int E) {
    int i = blockIdx.x * blockDim.x + threadIdx.x;
    if (i < E) atomicAdd(&deg[dst[i]], 1);
}

__global__ void make_dis(int* __restrict__ deg, int N) {
    int i = blockIdx.x * blockDim.x + threadIdx.x;
    if (i < N) {
        int d = deg[i];
        ((float*)deg)[i] = rsqrtf((float)(d + 1));
    }
}

// ---- hierarchical exclusive scan: deg[N] -> rp[N+1], cursor[N] ----
__global__ void scan_part(const int* __restrict__ deg, int* __restrict__ bsum, int N) {
    int tid = threadIdx.x, lane = tid & 63, wid = tid >> 6;
    int i = blockIdx.x * 256 + tid;
    int v = (i < N) ? deg[i] : 0;
#pragma unroll
    for (int off = 1; off < 64; off <<= 1) v += __shfl_xor(v, off, 64);
    __shared__ int ws[4];
    if (lane == 0) ws[wid] = v;
    __syncthreads();
    if (tid == 0) bsum[blockIdx.x] = ws[0] + ws[1] + ws[2] + ws[3];
}

__global__ __launch_bounds__(1024) void scan_top(const int* __restrict__ bsum, int nb,
                                                 int* __restrict__ boff, int* __restrict__ rp, int N) {
    __shared__ int wsum[16];
    int tid = threadIdx.x, lane = tid & 63, wid = tid >> 6;
    int v = (tid < nb) ? bsum[tid] : 0;
    int x = v;
#pragma unroll
    for (int off = 1; off < 64; off <<= 1) {
        int t = __shfl_up(x, off, 64);
        if (lane >= off) x += t;
    }
    if (lane == 63) wsum[wid] = x;
    __syncthreads();
    if (tid < 16) {
        int y = wsum[tid];
#pragma unroll
        for (int off = 1; off < 16; off <<= 1) {
            int t = __shfl_up(y, off, 16);
            if (tid >= off) y += t;
        }
        wsum[tid] = y;
    }
    __syncthreads();
    int base = wid ? wsum[wid - 1] : 0;
    if (tid < nb) boff[tid] = base + x - v;
    if (tid == 0) rp[N] = wsum[15];
}

__global__ void scan_final(const int* __restrict__ deg, const int* __restrict__ boff,
                           int* __restrict__ rp, int* __restrict__ cursor, int N) {
    int tid = threadIdx.x, lane = tid & 63, wid = tid >> 6;
    int i = blockIdx.x * 256 + tid;
    int v = (i < N) ? deg[i] : 0;
    int x = v;
#pragma unroll
    for (int off = 1; off < 64; off <<= 1) {
        int t = __shfl_up(x, off, 64);
        if (lane >= off) x += t;
    }
    __shared__ int wsum[4];
    if (lane == 63) wsum[wid] = x;
    __syncthreads();
    int base = boff[blockIdx.x];
    for (int ww = 0; ww < wid; ww++) base += wsum[ww];
    int ex = base + x - v;
    if (i < N) { rp[i] = ex; cursor[i] = ex; }
}

__global__ void csr_fill(const int* __restrict__ src, const int* __restrict__ dst,
                         int* __restrict__ cursor, int* __restrict__ csr_src, int E) {
    int e = blockIdx.x * blockDim.x + threadIdx.x;
    if (e < E) {
        int pos = atomicAdd(&cursor[dst[e]], 1);
        csr_src[pos] = src[e];
    }
}

// B[K x N] f32 -> transposed bf16 hi/lo [N][Kpad] (zero-padded past K)
__global__ void prep_b(const float* __restrict__ B, unsigned short* __restrict__ Bth,
                       unsigned short* __restrict__ Btl, int K, int N, int Kpad) {
    int idx = blockIdx.x * 256 + threadIdx.x;
    if (idx >= N * Kpad) return;
    int n = idx / Kpad, k = idx - n * Kpad;
    float v = (k < K) ? B[(size_t)k * N + n] : 0.f;
    unsigned short h = f2bf(v);
    Bth[idx] = h;
    Btl[idx] = f2bf(v - bf2f(h));
}

// C[M x BN] = A[M x K] @ B[K x BN], split-bf16 MFMA.
// BM=32, BK=32, KT = Kpad/32 K-tiles. A preloaded to registers (areg[KT], one float4
// per thread per tile); in-loop global traffic is only B (L2-resident weights).
template<int BN, int KT, int WROWS, int WCOLS>
__global__ __launch_bounds__(256) void gemm_mfma(
    const float* __restrict__ A, const unsigned short* __restrict__ Bth,
    const unsigned short* __restrict__ Btl, float* __restrict__ C,
    int M, int K, int Kpad) {
    constexpr int BM = 32, BK = 32, STR = BK + 8;
    constexpr int MF = (BM / WROWS) / 16;
    constexpr int NF = (BN / WCOLS) / 16;
    constexpr int TPB = 256 / BN;            // threads per B row
    constexpr int BCH = BK / TPB;            // ushorts per thread (B)
    constexpr int NV = BCH / 8;              // u16x8 vectors per thread (B)
    static_assert(BN * TPB == 256 && NV >= 1, "B staging mapping");

    __shared__ unsigned short AsH[BM][STR], AsL[BM][STR];
    __shared__ unsigned short BsH[BN][STR], BsL[BN][STR];

    const int tid = threadIdx.x;
    const int lane = tid & 63;
    const int w = tid >> 6;
    const int wrow = (w / WCOLS) * (BM / WROWS);
    const int wcol = (w % WCOLS) * (BN / WCOLS);
    const int bm = blockIdx.x * BM;
    const int lrow = lane & 15;
    const int lkq = (lane >> 4) * 8;
    const int ar = tid >> 3;                 // A row (32 rows, 8 thr/row)
    const int ak = (tid & 7) << 2;           // A k-offset within tile
    const int bn = tid / TPB;
    const int bkoff = (tid % TPB) * BCH;

    f32x4 acc[MF][NF] = {};

    // ---- preload ALL of A for this block's 32 rows into registers ----
    float4 areg[KT];
    {
        const int arow = bm + ar;
        const bool rok = arow < M;
        const float* rowp = &A[(size_t)arow * K];
#pragma unroll
        for (int kt = 0; kt < KT; kt++) {
            int kg = kt * 32 + ak;
            float4 v = make_float4(0.f, 0.f, 0.f, 0.f);
            if (rok) {
                if (kg + 3 < K) v = *(const float4*)&rowp[kg];
                else {
                    if (kg     < K) v.x = rowp[kg];
                    if (kg + 1 < K) v.y = rowp[kg + 1];
                    if (kg + 2 < K) v.z = rowp[kg + 2];
                }
            }
            areg[kt] = v;
        }
    }

    u16x8 bh[NV], bl[NV];
    auto loadB = [&](int kt) {
        const size_t bo = (size_t)bn * Kpad + kt * 32 + bkoff;
#pragma unroll
        for (int v = 0; v < NV; v++) {
            bh[v] = *(const u16x8*)&Bth[bo + v * 8];
            bl[v] = *(const u16x8*)&Btl[bo + v * 8];
        }
    };
    loadB(0);

    for (int kt = 0; kt < KT; kt++) {
        // stage A tile from registers (f32 -> bf16 hi/lo)
        {
            float4 v = areg[kt];
            ushort4 h4, l4;
            h4.x = f2bf(v.x); l4.x = f2bf(v.x - bf2f(h4.x));
            h4.y = f2bf(v.y); l4.y = f2bf(v.y - bf2f(h4.y));
            h4.z = f2bf(v.z); l4.z = f2bf(v.z - bf2f(h4.z));
            h4.w = f2bf(v.w); l4.w = f2bf(v.w - bf2f(h4.w));
            *(ushort4*)&AsH[ar][ak] = h4;
            *(ushort4*)&AsL[ar][ak] = l4;
        }
        // stage B tile from prefetch registers
#pragma unroll
        for (int v = 0; v < NV; v++) {
            *(u16x8*)&BsH[bn][bkoff + v * 8] = bh[v];
            *(u16x8*)&BsL[bn][bkoff + v * 8] = bl[v];
        }
        __syncthreads();
        if (kt + 1 < KT) loadB(kt + 1);      // L2-resident weight prefetch
        short8 ah[MF], al[MF], bhf[NF], blf[NF];
#pragma unroll
        for (int m = 0; m < MF; m++) {
            ah[m] = *(const short8*)&AsH[wrow + m * 16 + lrow][lkq];
            al[m] = *(const short8*)&AsL[wrow + m * 16 + lrow][lkq];
        }
#pragma unroll
        for (int n = 0; n < NF; n++) {
            bhf[n] = *(const short8*)&BsH[wcol + n * 16 + lrow][lkq];
            blf[n] = *(const short8*)&BsL[wcol + n * 16 + lrow][lkq];
        }
#pragma unroll
        for (int m = 0; m < MF; m++)
#pragma unroll
            for (int n = 0; n < NF; n++) {
                acc[m][n] = __builtin_amdgcn_mfma_f32_16x16x32_bf16(ah[m], bhf[n], acc[m][n], 0, 0, 0);
                acc[m][n] = __builtin_amdgcn_mfma_f32_16x16x32_bf16(al[m], bhf[n], acc[m][n], 0, 0, 0);
                acc[m][n] = __builtin_amdgcn_mfma_f32_16x16x32_bf16(ah[m], blf[n], acc[m][n], 0, 0, 0);
            }
        __syncthreads();
    }
    // store: C/D layout col=lane&15, row=(lane>>4)*4+q
#pragma unroll
    for (int m = 0; m < MF; m++)
#pragma unroll
        for (int n = 0; n < NF; n++)
#pragma unroll
            for (int q = 0; q < 4; q++) {
                int row = bm + wrow + m * 16 + (lane >> 4) * 4 + q;
                int col = wcol + n * 16 + (lane & 15);
                if (row < M) C[(size_t)row * BN + col] = acc[m][n][q];
            }
}

// one wave per dst node, lanes across 128 features (float2/lane); fused self-loop+bias+relu
__global__ __launch_bounds__(256) void gather128(
    const int* __restrict__ rp, const int* __restrict__ csr,
    const float* __restrict__ dis, const float* __restrict__ h,
    const float* __restrict__ bias, float* __restrict__ out, int Nn) {
    int n = (blockIdx.x * 256 + threadIdx.x) >> 6;
    int lane = threadIdx.x & 63;
    if (n >= Nn) return;
    int beg = rp[n], end = rp[n + 1];
    float a0x = 0.f, a0y = 0.f, a1x = 0.f, a1y = 0.f;
    float a2x = 0.f, a2y = 0.f, a3x = 0.f, a3y = 0.f;
    int j = beg;
    for (; j + 3 < end; j += 4) {
        int s0 = csr[j], s1 = csr[j + 1], s2 = csr[j + 2], s3 = csr[j + 3];
        float w0 = dis[s0], w1 = dis[s1], w2 = dis[s2], w3 = dis[s3];
        float2 v0 = *(const float2*)&h[(size_t)s0 * 128 + lane * 2];
        float2 v1 = *(const float2*)&h[(size_t)s1 * 128 + lane * 2];
        float2 v2 = *(const float2*)&h[(size_t)s2 * 128 + lane * 2];
        float2 v3 = *(const float2*)&h[(size_t)s3 * 128 + lane * 2];
        a0x = fmaf(w0, v0.x, a0x); a0y = fmaf(w0, v0.y, a0y);
        a1x = fmaf(w1, v1.x, a1x); a1y = fmaf(w1, v1.y, a1y);
        a2x = fmaf(w2, v2.x, a2x); a2y = fmaf(w2, v2.y, a2y);
        a3x = fmaf(w3, v3.x, a3x); a3y = fmaf(w3, v3.y, a3y);
    }
    for (; j < end; j++) {
        int s = csr[j];
        float ww = dis[s];
        float2 v = *(const float2*)&h[(size_t)s * 128 + lane * 2];
        a0x = fmaf(ww, v.x, a0x); a0y = fmaf(ww, v.y, a0y);
    }
    float accx = (a0x + a1x) + (a2x + a3x);
    float accy = (a0y + a1y) + (a2y + a3y);
    float dn = dis[n];
    float2 hv = *(const float2*)&h[(size_t)n * 128 + lane * 2];
    float2 o;
    o.x = fmaxf(dn * (accx + dn * hv.x) + bias[lane * 2], 0.f);
    o.y = fmaxf(dn * (accy + dn * hv.y) + bias[lane * 2 + 1], 0.f);
    *(float2*)&out[(size_t)n * 128 + lane * 2] = o;
}

// one wave per dst node, lanes across 64 features; fused self-loop+bias (no relu)
__global__ __launch_bounds__(256) void gather64(
    const int* __restrict__ rp, const int* __restrict__ csr,
    const float* __restrict__ dis, const float* __restrict__ h,
    const float* __restrict__ bias, float* __restrict__ out, int Nn) {
    int n = (blockIdx.x * 256 + threadIdx.x) >> 6;
    int lane = threadIdx.x & 63;
    if (n >= Nn) return;
    int beg = rp[n], end = rp[n + 1];
    float a0 = 0.f, a1 = 0.f, a2 = 0.f, a3 = 0.f;
    int j = beg;
    for (; j + 3 < end; j += 4) {
        int s0 = csr[j], s1 = csr[j + 1], s2 = csr[j + 2], s3 = csr[j + 3];
        float w0 = dis[s0], w1 = dis[s1], w2 = dis[s2], w3 = dis[s3];
        float v0 = h[(size_t)s0 * 64 + lane];
        float v1 = h[(size_t)s1 * 64 + lane];
        float v2 = h[(size_t)s2 * 64 + lane];
        float v3 = h[(size_t)s3 * 64 + lane];
        a0 = fmaf(w0, v0, a0); a1 = fmaf(w1, v1, a1);
        a2 = fmaf(w2, v2, a2); a3 = fmaf(w3, v3, a3);
    }
    for (; j < end; j++) {
        int s = csr[j];
        a0 = fmaf(dis[s], h[(size_t)s * 64 + lane], a0);
    }
    float acc = (a0 + a1) + (a2 + a3);
    float dn = dis[n];
    float hv = h[(size_t)n * 64 + lane];
    out[(size_t)n * 64 + lane] = dn * (acc + dn * hv) + bias[lane];
}

extern "C" void kernel_launch(void* const* d_in, const int* in_sizes, int n_in,
                              void* d_out, int out_size, void* d_ws, size_t ws_size,
                              hipStream_t stream) {
    const float* x  = (const float*)d_in[0];
    const int*   ei = (const int*)d_in[1];
    const float* W1 = (const float*)d_in[2];
    const float* b1 = (const float*)d_in[3];
    const float* W2 = (const float*)d_in[4];
    const float* b2 = (const float*)d_in[5];

    const int IN = 500, H = 128, OUT = 64;
    const int Nn = in_sizes[0] / IN;     // 50000
    const int E  = in_sizes[1] / 2;      // 800000
    const int* src  = ei;
    const int* dstp = ei + E;

    const int Npad = ((Nn + 63) / 64) * 64;
    const int nb   = (Nn + 255) / 256;
    const int K1p  = 512, K2p = 128;

    // workspace layout (int units)
    int*   degdis  = (int*)d_ws;                 // N: int deg -> float dis in place
    int*   rp      = degdis + Npad;              // N+1
    int*   bsum    = rp + Npad + 64;             // 1024
    int*   boff    = bsum + 1024;                // 1024
    int*   cursor  = boff + 1024;                // N
    int*   csr_src = cursor + Npad;              // E
    unsigned short* Bt1h = (unsigned short*)(csr_src + ((E + 63) / 64) * 64);  // 128*512
    unsigned short* Bt1l = Bt1h + H * K1p;
    unsigned short* Bt2h = Bt1l + H * K1p;       // 64*128
    unsigned short* Bt2l = Bt2h + OUT * K2p;
    float* h1      = (float*)(Bt2l + OUT * K2p);
    float* agg1    = h1 + (size_t)Nn * H;
    float* h2      = h1;                         // reuse after layer-1 gather
    float* dis     = (float*)degdis;
    float* out     = (float*)d_out;

    // ---- degree / CSR build ----
    fill_int<<<(Nn + 255) / 256, 256, 0, stream>>>(degdis, 0, Nn);
    deg_accum_i<<<(E + 255) / 256, 256, 0, stream>>>(dstp, degdis, E);
    scan_part<<<nb, 256, 0, stream>>>(degdis, bsum, Nn);
    scan_top<<<1, 1024, 0, stream>>>(bsum, nb, boff, rp, Nn);
    scan_final<<<nb, 256, 0, stream>>>(degdis, boff, rp, cursor, Nn);
    make_dis<<<(Nn + 255) / 256, 256, 0, stream>>>(degdis, Nn);
    csr_fill<<<(E + 255) / 256, 256, 0, stream>>>(src, dstp, cursor, csr_src, E);

    // ---- weight prep (bf16 hi/lo, transposed) ----
    prep_b<<<(H * K1p + 255) / 256, 256, 0, stream>>>(W1, Bt1h, Bt1l, IN, H, K1p);
    prep_b<<<(OUT * K2p + 255) / 256, 256, 0, stream>>>(W2, Bt2h, Bt2l, H, OUT, K2p);

    // ---- layer 1 ----
    gemm_mfma<128, 16, 2, 2><<<(Nn + 31) / 32, 256, 0, stream>>>(x, Bt1h, Bt1l, h1, Nn, IN, K1p);
    gather128<<<(Nn + 3) / 4, 256, 0, stream>>>(rp, csr_src, dis, h1, b1, agg1, Nn);

    // ---- layer 2 ----
    gemm_mfma<64, 4, 2, 2><<<(Nn + 31) / 32, 256, 0, stream>>>(agg1, Bt2h, Bt2l, h2, Nn, H, K2p);
    gather64<<<(Nn + 3) / 4, 256, 0, stream>>>(rp, csr_src, dis, h2, b2, out, Nn);
}